// Round 2
// baseline (11728.989 us; speedup 1.0000x reference)
//
#include <hip/hip_runtime.h>
#include <hip/hip_bf16.h>

// 2-layer GRU, B=128, S=2048, D=H=128, C=10.
// Reference dtype is float32; a runtime detector (kernel 1) probes x and
// writes a flag to d_ws so the main kernel handles EITHER fp32 or bf16
// input buffers (wave-uniform branch). Math: fp32 state, bf16 hi/lo-split
// MFMA activations, bf16(hi) weights resident in VGPRs.
//
// Decomposition: 8 persistent workgroups x 16 batch rows (recurrence is
// independent across batch -> zero cross-WG sync). 4 waves/WG; wave w owns
// hidden units [32w,32w+32) of BOTH layers (6 MFMA N-tiles = r/z/n weight
// rows), so gate math is lane-local in MFMA C/D layout. Only h crosses
// waves, via double-buffered LDS (2 barriers/step).

using bf16x8 = __attribute__((ext_vector_type(8))) short;
using f32x4  = __attribute__((ext_vector_type(4))) float;

#define S_LEN 2048
#define D_IN  128
#define HID   128
#define B_TOT 128
#define BC    16      // batch rows per workgroup (MFMA M)
#define PAD   136     // LDS row stride (elems): 272B -> max 2-way bank alias (free, m136)
#define NTHREADS 256

__device__ __forceinline__ float bf2f(short s) {
  unsigned int u = ((unsigned int)(unsigned short)s) << 16;
  float f; __builtin_memcpy(&f, &u, 4); return f;
}
__device__ __forceinline__ short f2bf(float f) {  // RNE
  unsigned int u; __builtin_memcpy(&u, &f, 4);
  u += 0x7fffu + ((u >> 16) & 1u);
  return (short)(u >> 16);
}
__device__ __forceinline__ float fast_sigmoid(float x) {
  return __builtin_amdgcn_rcpf(1.f + __expf(-x));   // saturates cleanly at +-inf
}
__device__ __forceinline__ float fast_tanh(float x) {
  return 2.f * __builtin_amdgcn_rcpf(1.f + __expf(-2.f * x)) - 1.f;
}

// ---- dtype detector: even 16-bit halves of fp32 data are uniform mantissa
// bits (rarely decode to a sane bf16 magnitude); of bf16 data they are
// N(0,1)-scaled bf16 values (almost always in range). ----
__global__ void detect_dtype(const unsigned short* __restrict__ x, int* __restrict__ flag) {
  const int lane = threadIdx.x;
  float v = fabsf(bf2f((short)x[2 * lane]));
  bool bf_like = (v > 0.00390625f) && (v < 16.f);
  unsigned long long m = __ballot(bf_like);
  if (lane == 0) flag[0] = (__popcll(m) >= 32) ? 0 : 1;   // 1 => fp32 inputs
}

// 6 N-tiles x 4 K-chunks of MFMA. NSEP: tiles 4,5 (n-gate) accumulate into
// accn (hp path must stay separate from xp for n = tanh(xn + r*hn)).
template<bool NSEP>
__device__ __forceinline__ void mm6(const bf16x8 (&a)[4], const bf16x8 (&W)[6][4],
                                    f32x4 (&acc)[6], f32x4 (&accn)[2]) {
#pragma unroll
  for (int tI = 0; tI < 6; ++tI) {
#pragma unroll
    for (int kq = 0; kq < 4; ++kq) {
      if (NSEP && tI >= 4)
        accn[tI - 4] = __builtin_amdgcn_mfma_f32_16x16x32_bf16(a[kq], W[tI][kq], accn[tI - 4], 0, 0, 0);
      else
        acc[tI]      = __builtin_amdgcn_mfma_f32_16x16x32_bf16(a[kq], W[tI][kq], acc[tI], 0, 0, 0);
    }
  }
}

// A-frag: lane holds A[m=lane&15][k=quad*8+j]; p = base + (lane&15)*PAD + quad*8
__device__ __forceinline__ void loadA(bf16x8 (&a)[4], const short* p) {
#pragma unroll
  for (int kq = 0; kq < 4; ++kq) a[kq] = *(const bf16x8*)(p + kq * 32);
}

// Gates + EMA update in C/D layout; writes bf16 hi/lo of h_new to LDS (A layout).
__device__ __forceinline__ void gru_gates(const f32x4 (&acc)[6], const f32x4 (&accn)[2],
                                          f32x4 (&hreg)[2],
                                          const float (&brz)[4], const float (&bn)[4],
                                          short* __restrict__ dhi, short* __restrict__ dlo,
                                          int u0, int nw, int quad) {
#pragma unroll
  for (int i = 0; i < 2; ++i) {
    const int col = u0 + i * 16 + nw;
#pragma unroll
    for (int rr = 0; rr < 4; ++rr) {
      float rv = fast_sigmoid(acc[i][rr] + brz[i]);
      float zv = fast_sigmoid(acc[2 + i][rr] + brz[2 + i]);
      float nv = fast_tanh((acc[4 + i][rr] + bn[i]) + rv * (accn[i][rr] + bn[2 + i]));
      float h  = (1.f - zv) * nv + zv * hreg[i][rr];
      hreg[i][rr] = h;
      short hi = f2bf(h);
      short lo = f2bf(h - bf2f(hi));
      const int row = quad * 4 + rr;
      dhi[row * PAD + col] = hi;
      dlo[row * PAD + col] = lo;
    }
  }
}

__global__ __launch_bounds__(NTHREADS, 1) void gru2_persistent(
    const void* __restrict__ x,
    const void* __restrict__ Wih0, const void* __restrict__ Whh0,
    const void* __restrict__ bih0, const void* __restrict__ bhh0,
    const void* __restrict__ Wih1, const void* __restrict__ Whh1,
    const void* __restrict__ bih1, const void* __restrict__ bhh1,
    const void* __restrict__ Wout, const void* __restrict__ bout,
    void* __restrict__ out, const int* __restrict__ flag)
{
  __shared__ __align__(16) short h0hi[2][BC * PAD], h0lo[2][BC * PAD];
  __shared__ __align__(16) short h1hi[2][BC * PAD], h1lo[2][BC * PAD];
  __shared__ __align__(16) short xbhi[2][BC * PAD], xblo[2][BC * PAD];

  const bool f32in = (flag[0] != 0);   // wave-uniform

  const int tid  = threadIdx.x;
  const int w    = tid >> 6;
  const int lane = tid & 63;
  const int nw   = lane & 15;
  const int quad = lane >> 4;
  const int u0   = w * 32;            // this wave's hidden-unit base
  const int b0   = blockIdx.x * BC;   // this WG's batch base

#define LDW(P,O) (f32in ? ((const float*)(P))[(O)] : bf2f(((const short*)(P))[(O)]))

  // ---- one-time init: zero h (parity 0) ----
  for (int i = tid; i < BC * PAD; i += NTHREADS) {
    h0hi[0][i] = 0; h0lo[0][i] = 0; h1hi[0][i] = 0; h1lo[0][i] = 0;
  }

  // per-thread x-staging geometry: row = tid>>4 (batch), cols (tid&15)*8..+7
  const size_t xelem = (size_t)(b0 + (tid >> 4)) * (size_t)(S_LEN * D_IN) + (size_t)((tid & 15) * 8);
  const int    xsoff = (tid >> 4) * PAD + (tid & 15) * 8;

  // x loader for timestep t -> bf16 hi/lo fragments (8 elems)
  auto load_x = [&](int t, bf16x8& xhi, bf16x8& xlo) {
    const size_t o = xelem + (size_t)t * D_IN;
    if (f32in) {
      const float* xf = (const float*)x;
      float4 v0 = *(const float4*)(xf + o);
      float4 v1 = *(const float4*)(xf + o + 4);
      float v[8] = {v0.x, v0.y, v0.z, v0.w, v1.x, v1.y, v1.z, v1.w};
#pragma unroll
      for (int e = 0; e < 8; ++e) {
        short hi = f2bf(v[e]);
        xhi[e] = hi;
        xlo[e] = f2bf(v[e] - bf2f(hi));
      }
    } else {
      xhi = *(const bf16x8*)((const short*)x + o);
#pragma unroll
      for (int e = 0; e < 8; ++e) xlo[e] = 0;
    }
  };

  { bf16x8 xh, xl; load_x(0, xh, xl);
    *(bf16x8*)&xbhi[0][xsoff] = xh; *(bf16x8*)&xblo[0][xsoff] = xl; }

  // ---- per-lane biases (regs) ----
  float brz0[4], bn0[4], brz1[4], bn1[4];
#pragma unroll
  for (int i = 0; i < 2; ++i) {
    const int col = u0 + i * 16 + nw;
    brz0[i]     = LDW(bih0, col)       + LDW(bhh0, col);
    brz0[2 + i] = LDW(bih0, 128 + col) + LDW(bhh0, 128 + col);
    bn0[i]      = LDW(bih0, 256 + col);
    bn0[2 + i]  = LDW(bhh0, 256 + col);
    brz1[i]     = LDW(bih1, col)       + LDW(bhh1, col);
    brz1[2 + i] = LDW(bih1, 128 + col) + LDW(bhh1, 128 + col);
    bn1[i]      = LDW(bih1, 256 + col);
    bn1[2 + i]  = LDW(bhh1, 256 + col);
  }

  // ---- weight B-frags (bf16 hi), VGPR-resident for the whole sequence ----
  // B-frag: lane holds W[rowbase+(lane&15)][kq*32+quad*8 ..+7]
  bf16x8 W0[6][4], Wh0f[6][4], W1[6][4], Wh1f[6][4];
#pragma unroll
  for (int tI = 0; tI < 6; ++tI) {
    const int rb = (tI >> 1) * 128 + u0 + (tI & 1) * 16 + nw;  // r,r,z,z,n,n tile rows
#pragma unroll
    for (int kq = 0; kq < 4; ++kq) {
      const size_t o = (size_t)rb * HID + kq * 32 + quad * 8;
#pragma unroll
      for (int e = 0; e < 8; ++e) {
        W0[tI][kq][e]   = f2bf(LDW(Wih0, o + e));
        Wh0f[tI][kq][e] = f2bf(LDW(Whh0, o + e));
        W1[tI][kq][e]   = f2bf(LDW(Wih1, o + e));
        Wh1f[tI][kq][e] = f2bf(LDW(Whh1, o + e));
      }
    }
  }

  f32x4 h0reg[2], h1reg[2];
  const f32x4 ZV = {0.f, 0.f, 0.f, 0.f};
#pragma unroll
  for (int i = 0; i < 2; ++i) { h0reg[i] = ZV; h1reg[i] = ZV; }

  __syncthreads();

  const int aoff = nw * PAD + quad * 8;

  for (int t = 0; t < S_LEN; ++t) {
    const int pr = t & 1, pw = pr ^ 1;

    // prefetch next x tile into regs (committed to LDS late in the step)
    const int t1 = (t + 1 < S_LEN) ? t + 1 : t;
    bf16x8 xh, xl; load_x(t1, xh, xl);

    // ---------------- layer 0: h0 = GRU0(x_t, h0) ----------------
    f32x4 acc[6], accn[2];
#pragma unroll
    for (int i = 0; i < 6; ++i) acc[i] = ZV;
#pragma unroll
    for (int i = 0; i < 2; ++i) accn[i] = ZV;

    bf16x8 a[4];
    loadA(a, &xbhi[pr][aoff]);  mm6<false>(a, W0,   acc, accn);  // x hi
    if (f32in) {
      loadA(a, &xblo[pr][aoff]); mm6<false>(a, W0,  acc, accn);  // x lo (fp32 path)
    }
    loadA(a, &h0hi[pr][aoff]);  mm6<true >(a, Wh0f, acc, accn);  // h0 hi
    loadA(a, &h0lo[pr][aoff]);  mm6<true >(a, Wh0f, acc, accn);  // h0 lo

    gru_gates(acc, accn, h0reg, brz0, bn0, h0hi[pw], h0lo[pw], u0, nw, quad);
    __syncthreads();   // h0_new visible for layer-1 A-frags

    // ---------------- layer 1: h1 = GRU1(h0_new, h1) ----------------
#pragma unroll
    for (int i = 0; i < 6; ++i) acc[i] = ZV;
#pragma unroll
    for (int i = 0; i < 2; ++i) accn[i] = ZV;

    loadA(a, &h0hi[pw][aoff]);  mm6<false>(a, W1,   acc, accn);  // xp1 hi
    loadA(a, &h0lo[pw][aoff]);  mm6<false>(a, W1,   acc, accn);  // xp1 lo
    loadA(a, &h1hi[pr][aoff]);  mm6<true >(a, Wh1f, acc, accn);  // hp1 hi
    loadA(a, &h1lo[pr][aoff]);  mm6<true >(a, Wh1f, acc, accn);  // hp1 lo

    // commit staged x for step t+1 (buffer pw == (t+1)&1; fenced by barrier below)
    *(bf16x8*)&xbhi[pw][xsoff] = xh;
    *(bf16x8*)&xblo[pw][xsoff] = xl;

    gru_gates(acc, accn, h1reg, brz1, bn1, h1hi[pw], h1lo[pw], u0, nw, quad);
    __syncthreads();   // end of step: h1_new + staged x visible; WAR-safe
  }

  // ---- logits: out = h1_last @ Wout^T + bout  (final h1 parity = 0, S even) ----
  if (tid < BC * 10) {
    const int b = tid / 10, c = tid % 10;
    float s = LDW(bout, c);
    const short* hh = &h1hi[0][b * PAD];
    const short* hl = &h1lo[0][b * PAD];
#pragma unroll 8
    for (int k = 0; k < HID; ++k)
      s += (bf2f(hh[k]) + bf2f(hl[k])) * LDW(Wout, c * HID + k);
    const size_t oidx = (size_t)(b0 + b) * 10 + c;
    if (f32in) ((float*)out)[oidx] = s;
    else       ((short*)out)[oidx] = f2bf(s);
  }
#undef LDW
}

extern "C" void kernel_launch(void* const* d_in, const int* in_sizes, int n_in,
                              void* d_out, int out_size, void* d_ws, size_t ws_size,
                              hipStream_t stream) {
  (void)in_sizes; (void)n_in; (void)out_size; (void)ws_size;
  int* flag = (int*)d_ws;

  detect_dtype<<<dim3(1), dim3(64), 0, stream>>>((const unsigned short*)d_in[0], flag);

  gru2_persistent<<<dim3(B_TOT / BC), dim3(NTHREADS), 0, stream>>>(
      d_in[0], d_in[1], d_in[2], d_in[3], d_in[4],
      d_in[5], d_in[6], d_in[7], d_in[8], d_in[9], d_in[10],
      d_out, flag);
}

// Round 3
// 5700.513 us; speedup vs baseline: 2.0575x; 2.0575x over previous
//
#include <hip/hip_runtime.h>
#include <hip/hip_bf16.h>

// 2-layer GRU, B=128, S=2048, D=H=128, C=10. Inputs fp32 (confirmed R2).
//
// Pipeline:
//  Phase 1 (all CUs): xp0[m,g] = x[m,:]@W_ih0[g,:] + bih0[g] (+bhh0[g] for r,z)
//     stored fp16 in d_ws (201 MB). Fully parallel GEMM, ~100us.
//  Phase 2 (8 persistent WGs x 16 batch rows): the serial recurrence with only
//     W_hh0, W_ih1, W_hh1 in VGPRs. 512 threads = 8 waves = 2 waves/SIMD
//     (__launch_bounds__(512,2) -> 256-VGPR budget, ~233 used -> no spill,
//     2-wave co-issue hides MFMA/VALU/trans latency).
//  Wave w owns 16 hidden units [16w,16w+16) of both layers (1 N-tile per gate);
//  gate math lane-local in MFMA C/D layout; h fp32 in regs + bf16 hi/lo in LDS
//  (A layout), double-buffered, 2 barriers/step.
// Fallback: if ws_size < 201MB, run the proven R2 single-kernel path (fp32).

using bf16x8 = __attribute__((ext_vector_type(8))) short;
using s16x4  = __attribute__((ext_vector_type(4))) short;
using f32x4  = __attribute__((ext_vector_type(4))) float;

#define S_LEN 2048
#define D_IN  128
#define HID   128
#define B_TOT 128
#define BC    16
#define PAD   136
#define G3    384
#define M_TOT (B_TOT * S_LEN)

__device__ __forceinline__ float bf2f(short s) {
  unsigned int u = ((unsigned int)(unsigned short)s) << 16;
  float f; __builtin_memcpy(&f, &u, 4); return f;
}
__device__ __forceinline__ short f2bf(float f) {  // RNE
  unsigned int u; __builtin_memcpy(&u, &f, 4);
  u += 0x7fffu + ((u >> 16) & 1u);
  return (short)(u >> 16);
}
__device__ __forceinline__ float fast_sigmoid(float x) {
  return __builtin_amdgcn_rcpf(1.f + __expf(-x));
}
__device__ __forceinline__ float fast_tanh(float x) {
  return 2.f * __builtin_amdgcn_rcpf(1.f + __expf(-2.f * x)) - 1.f;
}
__device__ __forceinline__ f32x4 MFMA(bf16x8 a, bf16x8 b, f32x4 c) {
  return __builtin_amdgcn_mfma_f32_16x16x32_bf16(a, b, c, 0, 0, 0);
}
__device__ __forceinline__ void loadA(bf16x8 (&a)[4], const short* p) {
#pragma unroll
  for (int kq = 0; kq < 4; ++kq) a[kq] = *(const bf16x8*)(p + kq * 32);
}

// ============================ Phase 1 =====================================
__global__ __launch_bounds__(256, 1) void xp0_gemm(
    const float* __restrict__ x, const float* __restrict__ Wih0,
    const float* __restrict__ bih0, const float* __restrict__ bhh0,
    _Float16* __restrict__ xp0)
{
  __shared__ short wlds[96 * PAD];   // current 96 gate-rows, bf16
  __shared__ float bfold[G3];

  const int tid = threadIdx.x;
  const int w = tid >> 6, lane = tid & 63, nw = lane & 15, quad = lane >> 4;
  const int m0 = blockIdx.x * 64 + w * 16;   // wave's 16 M-rows

  for (int g = tid; g < G3; g += 256)
    bfold[g] = bih0[g] + (g < 256 ? bhh0[g] : 0.f);   // fold bhh for r,z only

  // A-frags for this wave's x rows, fp32 -> bf16 hi/lo (exact-ish)
  bf16x8 ahi[4], alo[4];
  const int arow = m0 + nw;
#pragma unroll
  for (int kq = 0; kq < 4; ++kq) {
    const float* p = x + (size_t)arow * D_IN + kq * 32 + quad * 8;
    float4 v0 = *(const float4*)p, v1 = *(const float4*)(p + 4);
    float v[8] = {v0.x, v0.y, v0.z, v0.w, v1.x, v1.y, v1.z, v1.w};
#pragma unroll
    for (int e = 0; e < 8; ++e) {
      short h = f2bf(v[e]);
      ahi[kq][e] = h;
      alo[kq][e] = f2bf(v[e] - bf2f(h));
    }
  }

  for (int grp = 0; grp < 4; ++grp) {
    __syncthreads();   // WAR vs previous group's reads (covers bfold RAW too)
    for (int i = tid; i < 96 * 128 / 4; i += 256) {
      const int idx = i * 4, row = idx >> 7, cc = idx & 127;
      float4 v = *(const float4*)(Wih0 + (size_t)(grp * 96 + row) * 128 + cc);
      s16x4 s = { f2bf(v.x), f2bf(v.y), f2bf(v.z), f2bf(v.w) };
      *(s16x4*)&wlds[row * PAD + cc] = s;
    }
    __syncthreads();

    f32x4 acc[6];
#pragma unroll
    for (int i = 0; i < 6; ++i) acc[i] = (f32x4){0.f, 0.f, 0.f, 0.f};
#pragma unroll
    for (int tI = 0; tI < 6; ++tI)
#pragma unroll
      for (int kq = 0; kq < 4; ++kq) {
        bf16x8 b = *(const bf16x8*)&wlds[(tI * 16 + nw) * PAD + kq * 32 + quad * 8];
        acc[tI] = MFMA(ahi[kq], b, acc[tI]);
        acc[tI] = MFMA(alo[kq], b, acc[tI]);
      }

#pragma unroll
    for (int tI = 0; tI < 6; ++tI) {
      const int g = grp * 96 + tI * 16 + nw;
      const float bb = bfold[g];
#pragma unroll
      for (int rr = 0; rr < 4; ++rr) {
        const int m = m0 + quad * 4 + rr;
        xp0[(size_t)m * G3 + g] = (_Float16)(acc[tI][rr] + bb);
      }
    }
  }
}

// ============================ Phase 2 =====================================
__device__ __forceinline__ void mm3(const bf16x8 (&a)[4], const bf16x8 (&W)[3][4],
                                    f32x4& r, f32x4& z, f32x4& n) {
#pragma unroll
  for (int kq = 0; kq < 4; ++kq) {
    r = MFMA(a[kq], W[0][kq], r);
    z = MFMA(a[kq], W[1][kq], z);
    n = MFMA(a[kq], W[2][kq], n);
  }
}

__global__ __launch_bounds__(512, 2) void gru2_rec(
    const _Float16* __restrict__ xp0,
    const float* __restrict__ Whh0, const float* __restrict__ bhh0,
    const float* __restrict__ Wih1, const float* __restrict__ Whh1,
    const float* __restrict__ bih1, const float* __restrict__ bhh1,
    const float* __restrict__ Wout, const float* __restrict__ bout,
    float* __restrict__ out)
{
  __shared__ short h0hi[2][BC * PAD], h0lo[2][BC * PAD];
  __shared__ short h1hi[2][BC * PAD], h1lo[2][BC * PAD];

  const int tid  = threadIdx.x;
  const int w    = tid >> 6;        // 0..7
  const int lane = tid & 63;
  const int nw   = lane & 15;
  const int quad = lane >> 4;
  const int u0   = w * 16;
  const int col  = u0 + nw;         // this lane's hidden-unit column
  const int b0   = blockIdx.x * BC;

  for (int i = tid; i < BC * PAD; i += 512) {
    h0hi[0][i] = 0; h0lo[0][i] = 0; h1hi[0][i] = 0; h1lo[0][i] = 0;
  }

  // biases (layer-0 r/z/n input-side folded into xp0 already)
  const float b0n_h = bhh0[256 + col];
  const float b1r   = bih1[col]       + bhh1[col];
  const float b1z   = bih1[128 + col] + bhh1[128 + col];
  const float b1n_i = bih1[256 + col];
  const float b1n_h = bhh1[256 + col];

  // VGPR-resident weight B-frags (bf16 hi), 3 matrices x 3 gate tiles
  bf16x8 Wh0[3][4], Wi1[3][4], Wh1[3][4];
#pragma unroll
  for (int g = 0; g < 3; ++g) {
#pragma unroll
    for (int kq = 0; kq < 4; ++kq) {
      const size_t o = (size_t)(g * 128 + col) * HID + kq * 32 + quad * 8;
#pragma unroll
      for (int e = 0; e < 8; ++e) {
        Wh0[g][kq][e] = f2bf(Whh0[o + e]);
        Wi1[g][kq][e] = f2bf(Wih1[o + e]);
        Wh1[g][kq][e] = f2bf(Whh1[o + e]);
      }
    }
  }

  // xp0 addressing: lane reads (b0+quad*4+rr, gate g, t) -> 12 fp16 / step
  size_t xbase[4];
#pragma unroll
  for (int rr = 0; rr < 4; ++rr)
    xbase[rr] = (size_t)(b0 + quad * 4 + rr) * S_LEN * G3 + col;

  float P[12];
#pragma unroll
  for (int g = 0; g < 3; ++g)
#pragma unroll
    for (int rr = 0; rr < 4; ++rr)
      P[g * 4 + rr] = (float)xp0[xbase[rr] + g * 128];

  f32x4 h0r = {0.f, 0.f, 0.f, 0.f}, h1r = {0.f, 0.f, 0.f, 0.f};
  __syncthreads();

  const int aoff = nw * PAD + quad * 8;

  for (int t = 0; t < S_LEN; ++t) {
    const int pr = t & 1, pw = pr ^ 1;

    // prefetch xp for t+1 (consumed next step; 2 barriers hide latency)
    const int tn = (t + 1 < S_LEN) ? t + 1 : t;
    float Pn[12];
#pragma unroll
    for (int g = 0; g < 3; ++g)
#pragma unroll
      for (int rr = 0; rr < 4; ++rr)
        Pn[g * 4 + rr] = (float)xp0[xbase[rr] + (size_t)tn * G3 + g * 128];

    // -------- layer 0: hp = h0 @ Whh0^T --------
    f32x4 ar = {0,0,0,0}, az = {0,0,0,0}, ahn = {0,0,0,0};
    bf16x8 a[4];
    loadA(a, &h0hi[pr][aoff]); mm3(a, Wh0, ar, az, ahn);
    loadA(a, &h0lo[pr][aoff]); mm3(a, Wh0, ar, az, ahn);

#pragma unroll
    for (int rr = 0; rr < 4; ++rr) {
      float r = fast_sigmoid(P[0 + rr] + ar[rr]);
      float z = fast_sigmoid(P[4 + rr] + az[rr]);
      float n = fast_tanh(P[8 + rr] + r * (ahn[rr] + b0n_h));
      float h = (1.f - z) * n + z * h0r[rr];
      h0r[rr] = h;
      short hi = f2bf(h);
      const int row = quad * 4 + rr;
      h0hi[pw][row * PAD + col] = hi;
      h0lo[pw][row * PAD + col] = f2bf(h - bf2f(hi));
    }
    __syncthreads();

    // -------- layer 1: xp1 = h0new @ Wih1^T ; hp1 = h1 @ Whh1^T --------
    f32x4 br = {0,0,0,0}, bz = {0,0,0,0}, bxn = {0,0,0,0}, bhn = {0,0,0,0};
    loadA(a, &h0hi[pw][aoff]); mm3(a, Wi1, br, bz, bxn);
    loadA(a, &h0lo[pw][aoff]); mm3(a, Wi1, br, bz, bxn);
    loadA(a, &h1hi[pr][aoff]); mm3(a, Wh1, br, bz, bhn);
    loadA(a, &h1lo[pr][aoff]); mm3(a, Wh1, br, bz, bhn);

#pragma unroll
    for (int rr = 0; rr < 4; ++rr) {
      float r = fast_sigmoid(br[rr] + b1r);
      float z = fast_sigmoid(bz[rr] + b1z);
      float n = fast_tanh(bxn[rr] + b1n_i + r * (bhn[rr] + b1n_h));
      float h = (1.f - z) * n + z * h1r[rr];
      h1r[rr] = h;
      short hi = f2bf(h);
      const int row = quad * 4 + rr;
      h1hi[pw][row * PAD + col] = hi;
      h1lo[pw][row * PAD + col] = f2bf(h - bf2f(hi));
    }
#pragma unroll
    for (int i = 0; i < 12; ++i) P[i] = Pn[i];
    __syncthreads();
  }

  // logits from final h1 (parity 0; S even)
  if (tid < BC * 10) {
    const int b = tid / 10, c = tid % 10;
    float s = bout[c];
    const short* hh = &h1hi[0][b * PAD];
    const short* hl = &h1lo[0][b * PAD];
#pragma unroll 8
    for (int k = 0; k < HID; ++k)
      s += (bf2f(hh[k]) + bf2f(hl[k])) * Wout[c * HID + k];
    out[(size_t)(b0 + b) * 10 + c] = s;
  }
}

// ==================== Fallback: R2 kernel, fp32 hard-coded =================
template<bool NSEP>
__device__ __forceinline__ void mm6(const bf16x8 (&a)[4], const bf16x8 (&W)[6][4],
                                    f32x4 (&acc)[6], f32x4 (&accn)[2]) {
#pragma unroll
  for (int tI = 0; tI < 6; ++tI)
#pragma unroll
    for (int kq = 0; kq < 4; ++kq) {
      if (NSEP && tI >= 4) accn[tI - 4] = MFMA(a[kq], W[tI][kq], accn[tI - 4]);
      else                 acc[tI]      = MFMA(a[kq], W[tI][kq], acc[tI]);
    }
}

__global__ __launch_bounds__(256, 1) void gru2_v1(
    const float* __restrict__ x,
    const float* __restrict__ Wih0, const float* __restrict__ Whh0,
    const float* __restrict__ bih0, const float* __restrict__ bhh0,
    const float* __restrict__ Wih1, const float* __restrict__ Whh1,
    const float* __restrict__ bih1, const float* __restrict__ bhh1,
    const float* __restrict__ Wout, const float* __restrict__ bout,
    float* __restrict__ out)
{
  __shared__ short h0hi[2][BC * PAD], h0lo[2][BC * PAD];
  __shared__ short h1hi[2][BC * PAD], h1lo[2][BC * PAD];
  __shared__ short xbhi[2][BC * PAD], xblo[2][BC * PAD];

  const int tid = threadIdx.x, w = tid >> 6, lane = tid & 63;
  const int nw = lane & 15, quad = lane >> 4, u0 = w * 32;
  const int b0 = blockIdx.x * BC;

  for (int i = tid; i < BC * PAD; i += 256) {
    h0hi[0][i] = 0; h0lo[0][i] = 0; h1hi[0][i] = 0; h1lo[0][i] = 0;
  }
  const size_t xelem = (size_t)(b0 + (tid >> 4)) * (size_t)(S_LEN * D_IN) + (size_t)((tid & 15) * 8);
  const int xsoff = (tid >> 4) * PAD + (tid & 15) * 8;

  auto load_x = [&](int t, bf16x8& xhi, bf16x8& xlo) {
    const size_t o = xelem + (size_t)t * D_IN;
    float4 v0 = *(const float4*)(x + o), v1 = *(const float4*)(x + o + 4);
    float v[8] = {v0.x, v0.y, v0.z, v0.w, v1.x, v1.y, v1.z, v1.w};
#pragma unroll
    for (int e = 0; e < 8; ++e) {
      short h = f2bf(v[e]); xhi[e] = h; xlo[e] = f2bf(v[e] - bf2f(h));
    }
  };
  { bf16x8 xh, xl; load_x(0, xh, xl);
    *(bf16x8*)&xbhi[0][xsoff] = xh; *(bf16x8*)&xblo[0][xsoff] = xl; }

  float brz0[4], bn0[4], brz1[4], bn1[4];
#pragma unroll
  for (int i = 0; i < 2; ++i) {
    const int c = u0 + i * 16 + nw;
    brz0[i] = bih0[c] + bhh0[c];     brz0[2 + i] = bih0[128 + c] + bhh0[128 + c];
    bn0[i] = bih0[256 + c];          bn0[2 + i] = bhh0[256 + c];
    brz1[i] = bih1[c] + bhh1[c];     brz1[2 + i] = bih1[128 + c] + bhh1[128 + c];
    bn1[i] = bih1[256 + c];          bn1[2 + i] = bhh1[256 + c];
  }

  bf16x8 W0[6][4], Wh0f[6][4], W1[6][4], Wh1f[6][4];
#pragma unroll
  for (int tI = 0; tI < 6; ++tI) {
    const int rb = (tI >> 1) * 128 + u0 + (tI & 1) * 16 + nw;
#pragma unroll
    for (int kq = 0; kq < 4; ++kq) {
      const size_t o = (size_t)rb * HID + kq * 32 + quad * 8;
#pragma unroll
      for (int e = 0; e < 8; ++e) {
        W0[tI][kq][e] = f2bf(Wih0[o + e]);  Wh0f[tI][kq][e] = f2bf(Whh0[o + e]);
        W1[tI][kq][e] = f2bf(Wih1[o + e]);  Wh1f[tI][kq][e] = f2bf(Whh1[o + e]);
      }
    }
  }

  f32x4 h0reg[2] = {{0,0,0,0},{0,0,0,0}}, h1reg[2] = {{0,0,0,0},{0,0,0,0}};
  const f32x4 ZV = {0.f, 0.f, 0.f, 0.f};
  __syncthreads();
  const int aoff = nw * PAD + quad * 8;

  auto gates = [&](const f32x4 (&acc)[6], const f32x4 (&accn)[2], f32x4 (&hreg)[2],
                   const float (&brz)[4], const float (&bn)[4],
                   short* dhi, short* dlo) {
#pragma unroll
    for (int i = 0; i < 2; ++i) {
      const int c = u0 + i * 16 + nw;
#pragma unroll
      for (int rr = 0; rr < 4; ++rr) {
        float rv = fast_sigmoid(acc[i][rr] + brz[i]);
        float zv = fast_sigmoid(acc[2 + i][rr] + brz[2 + i]);
        float nv = fast_tanh((acc[4 + i][rr] + bn[i]) + rv * (accn[i][rr] + bn[2 + i]));
        float h = (1.f - zv) * nv + zv * hreg[i][rr];
        hreg[i][rr] = h;
        short hi = f2bf(h);
        const int row = quad * 4 + rr;
        dhi[row * PAD + c] = hi;
        dlo[row * PAD + c] = f2bf(h - bf2f(hi));
      }
    }
  };

  for (int t = 0; t < S_LEN; ++t) {
    const int pr = t & 1, pw = pr ^ 1;
    const int t1 = (t + 1 < S_LEN) ? t + 1 : t;
    bf16x8 xh, xl; load_x(t1, xh, xl);

    f32x4 acc[6], accn[2];
#pragma unroll
    for (int i = 0; i < 6; ++i) acc[i] = ZV;
#pragma unroll
    for (int i = 0; i < 2; ++i) accn[i] = ZV;
    bf16x8 a[4];
    loadA(a, &xbhi[pr][aoff]); mm6<false>(a, W0, acc, accn);
    loadA(a, &xblo[pr][aoff]); mm6<false>(a, W0, acc, accn);
    loadA(a, &h0hi[pr][aoff]); mm6<true >(a, Wh0f, acc, accn);
    loadA(a, &h0lo[pr][aoff]); mm6<true >(a, Wh0f, acc, accn);
    gates(acc, accn, h0reg, brz0, bn0, h0hi[pw], h0lo[pw]);
    __syncthreads();

#pragma unroll
    for (int i = 0; i < 6; ++i) acc[i] = ZV;
#pragma unroll
    for (int i = 0; i < 2; ++i) accn[i] = ZV;
    loadA(a, &h0hi[pw][aoff]); mm6<false>(a, W1, acc, accn);
    loadA(a, &h0lo[pw][aoff]); mm6<false>(a, W1, acc, accn);
    loadA(a, &h1hi[pr][aoff]); mm6<true >(a, Wh1f, acc, accn);
    loadA(a, &h1lo[pr][aoff]); mm6<true >(a, Wh1f, acc, accn);
    *(bf16x8*)&xbhi[pw][xsoff] = xh;
    *(bf16x8*)&xblo[pw][xsoff] = xl;
    gates(acc, accn, h1reg, brz1, bn1, h1hi[pw], h1lo[pw]);
    __syncthreads();
  }

  if (tid < BC * 10) {
    const int b = tid / 10, c = tid % 10;
    float s = bout[c];
    const short* hh = &h1hi[0][b * PAD];
    const short* hl = &h1lo[0][b * PAD];
#pragma unroll 8
    for (int k = 0; k < HID; ++k)
      s += (bf2f(hh[k]) + bf2f(hl[k])) * Wout[c * HID + k];
    out[(size_t)(b0 + b) * 10 + c] = s;
  }
}

// ============================ Host =========================================
extern "C" void kernel_launch(void* const* d_in, const int* in_sizes, int n_in,
                              void* d_out, int out_size, void* d_ws, size_t ws_size,
                              hipStream_t stream) {
  (void)in_sizes; (void)n_in; (void)out_size;
  const float* x    = (const float*)d_in[0];
  const float* Wih0 = (const float*)d_in[1];
  const float* Whh0 = (const float*)d_in[2];
  const float* bih0 = (const float*)d_in[3];
  const float* bhh0 = (const float*)d_in[4];
  const float* Wih1 = (const float*)d_in[5];
  const float* Whh1 = (const float*)d_in[6];
  const float* bih1 = (const float*)d_in[7];
  const float* bhh1 = (const float*)d_in[8];
  const float* Wout = (const float*)d_in[9];
  const float* bout = (const float*)d_in[10];
  float* out = (float*)d_out;

  const size_t XPB = (size_t)M_TOT * G3 * sizeof(_Float16);  // 201 MB
  if (ws_size >= XPB) {
    xp0_gemm<<<dim3(M_TOT / 64), dim3(256), 0, stream>>>(
        x, Wih0, bih0, bhh0, (_Float16*)d_ws);
    gru2_rec<<<dim3(B_TOT / BC), dim3(512), 0, stream>>>(
        (const _Float16*)d_ws, Whh0, bhh0, Wih1, Whh1, bih1, bhh1, Wout, bout, out);
  } else {
    gru2_v1<<<dim3(B_TOT / BC), dim3(256), 0, stream>>>(
        x, Wih0, Whh0, bih0, bhh0, Wih1, Whh1, bih1, bhh1, Wout, bout, out);
  }
}